// Round 11
// baseline (22.311 us; speedup 1.0000x reference)
//
#include <hip/hip_runtime.h>
#include <math.h>

// Problem constants from the reference
#define BB 32
#define NN 8
#define TT 52
#define HH 224
#define WW 224
#define PP 100    // 10x10 local grid; point p: slot A = lane p (p<64), slot B = lane p-64
#define NWAVE 16  // waves per block (1024 threads)
#define TPB 26    // trajectories per block (TT/2); 2 blocks per (b,n) output
#define MAGICHI 0x5A5A5A5AULL
#define CLEAN   0xAAAAAAAAAAAAAAAAULL   // == harness poison pattern

__device__ __forceinline__ float rlane_f(float v, int l) {
    return __int_as_float(__builtin_amdgcn_readlane(__float_as_int(v), l));
}

// 2 blocks/CU x 16 waves = 32 waves/CU requires VGPR <= 64: min 8 waves/EU.
__global__ __launch_bounds__(NWAVE * 64, 8) void mapcoll_fused(
    const float* __restrict__ x,        // (B,N,T,6)
    const float* __restrict__ dmap,     // (B,H,W)
    const float* __restrict__ extent,   // (B,3)
    const float* __restrict__ rfa,      // (B,3,3)
    unsigned long long* __restrict__ ws,// (B*N) u64 rendezvous slots (poison-init)
    float* __restrict__ out)            // (B*N)
{
    const int bid  = blockIdx.x;        // 0..511
    const int bn   = bid >> 1;          // 0..255
    const int half = bid & 1;
    const int b    = bn >> 3;           // NN == 8
    const int lane = threadIdx.x & 63;
    const int wvu  = __builtin_amdgcn_readfirstlane((int)(threadIdx.x >> 6));

    __shared__ float s_part[NWAVE];

    // ---- per-b uniforms (scalar loads) ----
    const float lwx = extent[b * 3 + 0];
    const float lwy = extent[b * 3 + 1];
    const float inv_diag = 1.0f / sqrtf(lwx * lwx + lwy * lwy);
    const float r00 = rfa[b*9+0], r01 = rfa[b*9+1], r02 = rfa[b*9+2];
    const float r10 = rfa[b*9+3], r11 = rfa[b*9+4], r12 = rfa[b*9+5];
    const float* __restrict__ map_b = dmap + (size_t)b * (HH * WW);
    // Rigid-motion invariance: |a_p - a_q|^2 = ((i_p-i_q)*sx)^2 + ((j_p-j_q)*sy)^2
    const float sx  = lwx * (1.0f / 9.0f);
    const float sy  = lwy * (1.0f / 9.0f);
    const float sy2 = sy * sy;

    // ---- lane-parallel prologue: lane t<26 loads pos/yaw, computes sin/cos ----
    float ppx = 0.0f, ppy = 0.0f, psn = 0.0f, pcs = 1.0f;
    if (lane < TPB) {
        const int base = (bn * TT + half * TPB + lane) * 6;
        const float2 p2 = *reinterpret_cast<const float2*>(x + base);
        ppx = p2.x; ppy = p2.y;
        const float yw = x[base + 3];
        psn = __sinf(yw);
        pcs = __cosf(yw);
    }

    // ---- per-lane footprint geometry (t-independent) ----
    const int iA = lane / 10, jA = lane - iA * 10;
    const int pB = lane + 64;
    const int iB = pB / 10,   jB = pB - iB * 10;
    const int invjA = 9 - jA, invjB = 9 - jB;
    const float p0A = (-0.5f + (float)iA * (1.0f/9.0f)) * lwx;
    const float p1A = (-0.5f + (float)jA * (1.0f/9.0f)) * lwy;
    const float p0B = (-0.5f + (float)iB * (1.0f/9.0f)) * lwx;
    const float p1B = (-0.5f + (float)jB * (1.0f/9.0f)) * lwy;
    const bool hasB = (lane < PP - 64);   // 36 lanes own a B point

    // t distribution over 16 waves: waves 0..9 -> 2 t's, waves 10..15 -> 1 t (26 total)
    const int kn = (wvu < 10) ? 2 : 1;
    const int t0 = (wvu < 10) ? (wvu * 2) : (20 + (wvu - 10));

    float acc = 0.0f;
    #pragma unroll
    for (int k = 0; k < 2; ++k) {
        if (k >= kn) continue;                 // wave-uniform
        const int t = t0 + k;                  // local t index (0..25)
        const float posx = rlane_f(ppx, t);
        const float posy = rlane_f(ppy, t);
        const float sn   = rlane_f(psn, t);
        const float cs   = rlane_f(pcs, t);

        // transform + rasterize + gather (both slots issued before use)
        const float axA = p0A * cs - p1A * sn + posx;
        const float ayA = p0A * sn + p1A * cs + posy;
        float vAv, vBv = 1.0f;
        {
            const float fx = axA * r00 + ayA * r01 + r02;
            const float fy = axA * r10 + ayA * r11 + r12;
            int ix = (int)fx, iy = (int)fy;    // trunc cast, then clip (ref semantics)
            ix = ix < 0 ? 0 : (ix > WW - 1 ? WW - 1 : ix);
            iy = iy < 0 ? 0 : (iy > HH - 1 ? HH - 1 : iy);
            vAv = map_b[iy * WW + ix];
        }
        if (hasB) {
            const float axB = p0B * cs - p1B * sn + posx;
            const float ayB = p0B * sn + p1B * cs + posy;
            const float fx = axB * r00 + ayB * r01 + r02;
            const float fy = axB * r10 + ayB * r11 + r12;
            int ix = (int)fx, iy = (int)fy;
            ix = ix < 0 ? 0 : (ix > WW - 1 ? WW - 1 : ix);
            iy = iy < 0 ? 0 : (iy > HH - 1 ? HH - 1 : iy);
            vBv = map_b[iy * WW + ix];
        }

        const int clA = (vAv == 0.0f) ? 1 : 0; // offroad==1 <=> drv==0 ({0,1} map)
        const int clB = (vBv == 0.0f) ? 1 : 0;
        const unsigned long long cmA = __ballot(clA);
        const unsigned long long cmB = __ballot(clB);
        const int ncoll = __popcll(cmA) + __popcll(cmB);
        if (ncoll == 0 || ncoll == PP) continue;   // overlap false -> contributes 0

        // 10-bit FREE-column mask per grid row (wave-uniform -> SALU)
        const unsigned long long fA = ~cmA;                           // points 0..63
        const unsigned long long fB = (~cmB) & ((1ull << 36) - 1ull); // points 64..99
        unsigned rows[10], revs[10];
        #pragma unroll
        for (int r = 0; r < 6; ++r) rows[r] = (unsigned)((fA >> (10 * r)) & 0x3FFull);
        rows[6] = (unsigned)(((fA >> 60) | (fB << 4)) & 0x3FFull);
        #pragma unroll
        for (int r = 7; r < 10; ++r) rows[r] = (unsigned)((fB >> (10 * r - 64)) & 0x3FFull);
        #pragma unroll
        for (int r = 0; r < 10; ++r) revs[r] = __brev(rows[r]) >> 22;   // 10-bit reverse

        // Merged A/B per-row nearest-free-column min.
        // Empty row -> marker bit 25 -> d=25 -> 625*sy2 >= 30.9 > max real d2 (~26.9)
        float mA = 1e30f, mB = 1e30f;
        float diA = (float)iA * sx;
        float diB = (float)iB * sx;
        #pragma unroll
        for (int r = 0; r < 10; ++r) {
            const unsigned tA = (rows[r] >> jA) | (revs[r] >> invjA) | (1u << 25);
            const unsigned tB = (rows[r] >> jB) | (revs[r] >> invjB) | (1u << 25);
            const unsigned dA = __builtin_ctz(tA);
            const unsigned dB = __builtin_ctz(tB);
            mA = fminf(mA, fmaf(diA, diA, (float)(dA * dA) * sy2));
            mB = fminf(mB, fmaf(diB, diB, (float)(dB * dB) * sy2));
            diA -= sx;
            diB -= sx;
        }
        acc += clA ? (1.0f - sqrtf(mA) * inv_diag) : 0.0f;
        acc += clB ? (1.0f - sqrtf(mB) * inv_diag) : 0.0f;
    }

    // ---- wave reduce -> LDS -> block reduce ----
    #pragma unroll
    for (int off = 32; off > 0; off >>= 1) acc += __shfl_down(acc, off);
    if (lane == 0) s_part[wvu] = acc;
    __syncthreads();
    if (threadIdx.x < 64) {
        float v = (lane < NWAVE) ? s_part[lane] : 0.0f;
        v += __shfl_down(v, 8);
        v += __shfl_down(v, 4);
        v += __shfl_down(v, 2);
        v += __shfl_down(v, 1);
        if (lane == 0) {
            // Tagged-exchange rendezvous: no spin, no memset, self-cleaning.
            // First arriver deposits its partial; second combines and writes out,
            // then restores the slot to the poison pattern (ready for next call).
            const unsigned long long tagged =
                (MAGICHI << 32) | (unsigned long long)__float_as_uint(v);
            const unsigned long long old = __hip_atomic_exchange(
                &ws[bn], tagged, __ATOMIC_ACQ_REL, __HIP_MEMORY_SCOPE_AGENT);
            if ((old >> 32) == MAGICHI) {
                const float other = __uint_as_float((unsigned)(old & 0xFFFFFFFFull));
                out[bn] = v + other;   // commutative -> bit-deterministic
                __hip_atomic_store(&ws[bn], CLEAN,
                                   __ATOMIC_RELEASE, __HIP_MEMORY_SCOPE_AGENT);
            }
        }
    }
}

extern "C" void kernel_launch(void* const* d_in, const int* in_sizes, int n_in,
                              void* d_out, int out_size, void* d_ws, size_t ws_size,
                              hipStream_t stream) {
    const float* x      = (const float*)d_in[0];
    const float* dmap   = (const float*)d_in[1];
    const float* extent = (const float*)d_in[2];
    const float* rfa    = (const float*)d_in[3];
    float* out = (float*)d_out;
    unsigned long long* ws = (unsigned long long*)d_ws;   // 256 x u64 = 2 KB

    mapcoll_fused<<<BB * NN * 2, NWAVE * 64, 0, stream>>>(x, dmap, extent, rfa, ws, out);
}

// Round 12
// 14.672 us; speedup vs baseline: 1.5207x; 1.5207x over previous
//
#include <hip/hip_runtime.h>
#include <math.h>

// Problem constants from the reference
#define BB 32
#define NN 8
#define TT 52
#define HH 224
#define WW 224
#define PP 100    // 10x10 local grid; point p: slot A = lane p (p<64), slot B = lane p-64
#define NWAVE 16  // waves per block (1024 threads)
#define TPB 26    // trajectories per block (TT/2); 2 blocks per (b,n) output
#define MAGICHI 0x5A5A5A5AULL
#define CLEAN   0xAAAAAAAAAAAAAAAAULL   // == harness poison pattern

__device__ __forceinline__ float rlane_f(float v, int l) {
    return __int_as_float(__builtin_amdgcn_readlane(__float_as_int(v), l));
}

__global__ __launch_bounds__(NWAVE * 64) void mapcoll_fused(
    const float* __restrict__ x,        // (B,N,T,6)
    const float* __restrict__ dmap,     // (B,H,W)
    const float* __restrict__ extent,   // (B,3)
    const float* __restrict__ rfa,      // (B,3,3)
    unsigned long long* __restrict__ ws,// (B*N) u64 rendezvous slots (poison-init)
    float* __restrict__ out)            // (B*N)
{
    const int bid  = blockIdx.x;        // 0..511
    const int bn   = bid >> 1;          // 0..255
    const int half = bid & 1;
    const int b    = bn >> 3;           // NN == 8
    const int lane = threadIdx.x & 63;
    const int wvu  = __builtin_amdgcn_readfirstlane((int)(threadIdx.x >> 6));

    __shared__ float s_part[NWAVE];

    // ---- per-b uniforms (scalar loads) ----
    const float lwx = extent[b * 3 + 0];
    const float lwy = extent[b * 3 + 1];
    const float inv_diag = 1.0f / sqrtf(lwx * lwx + lwy * lwy);
    const float r00 = rfa[b*9+0], r01 = rfa[b*9+1], r02 = rfa[b*9+2];
    const float r10 = rfa[b*9+3], r11 = rfa[b*9+4], r12 = rfa[b*9+5];
    const float* __restrict__ map_b = dmap + (size_t)b * (HH * WW);
    // Rigid-motion invariance: |a_p - a_q|^2 = ((i_p-i_q)*sx)^2 + ((j_p-j_q)*sy)^2
    const float sx  = lwx * (1.0f / 9.0f);
    const float sy  = lwy * (1.0f / 9.0f);
    const float sy2 = sy * sy;

    // ---- lane-parallel prologue: lane t<26 loads pos/yaw, computes sin/cos ----
    float ppx = 0.0f, ppy = 0.0f, psn = 0.0f, pcs = 1.0f;
    if (lane < TPB) {
        const int base = (bn * TT + half * TPB + lane) * 6;
        const float2 p2 = *reinterpret_cast<const float2*>(x + base);
        ppx = p2.x; ppy = p2.y;
        const float yw = x[base + 3];
        psn = __sinf(yw);
        pcs = __cosf(yw);
    }

    // ---- per-lane footprint geometry (t-independent) ----
    const int iA = lane / 10, jA = lane - iA * 10;
    const int pB = lane + 64;
    const int iB = pB / 10,   jB = pB - iB * 10;
    const int invjA = 9 - jA, invjB = 9 - jB;
    const float p0A = (-0.5f + (float)iA * (1.0f/9.0f)) * lwx;
    const float p1A = (-0.5f + (float)jA * (1.0f/9.0f)) * lwy;
    const float p0B = (-0.5f + (float)iB * (1.0f/9.0f)) * lwx;
    const float p1B = (-0.5f + (float)jB * (1.0f/9.0f)) * lwy;
    const bool hasB = (lane < PP - 64);   // 36 lanes own a B point

    // t distribution over 16 waves: waves 0..9 -> 2 t's, waves 10..15 -> 1 t (26 total)
    const int kn = (wvu < 10) ? 2 : 1;
    const int t0 = (wvu < 10) ? (wvu * 2) : (20 + (wvu - 10));

    // ---- phase 1: transform + rasterize + issue ALL gathers before any use ----
    float vA[2], vB[2];
    #pragma unroll
    for (int k = 0; k < 2; ++k) {
        vA[k] = 1.0f;                       // "free" for skipped slots
        vB[k] = 1.0f;
        if (k < kn) {                       // wave-uniform guard
            const int t = t0 + k;
            const float posx = rlane_f(ppx, t);
            const float posy = rlane_f(ppy, t);
            const float sn   = rlane_f(psn, t);
            const float cs   = rlane_f(pcs, t);
            const float axA = p0A * cs - p1A * sn + posx;
            const float ayA = p0A * sn + p1A * cs + posy;
            {
                const float fx = axA * r00 + ayA * r01 + r02;
                const float fy = axA * r10 + ayA * r11 + r12;
                int ix = (int)fx, iy = (int)fy;    // trunc cast, then clip (ref semantics)
                ix = ix < 0 ? 0 : (ix > WW - 1 ? WW - 1 : ix);
                iy = iy < 0 ? 0 : (iy > HH - 1 ? HH - 1 : iy);
                vA[k] = map_b[iy * WW + ix];
            }
            if (hasB) {
                const float axB = p0B * cs - p1B * sn + posx;
                const float ayB = p0B * sn + p1B * cs + posy;
                const float fx = axB * r00 + ayB * r01 + r02;
                const float fy = axB * r10 + ayB * r11 + r12;
                int ix = (int)fx, iy = (int)fy;
                ix = ix < 0 ? 0 : (ix > WW - 1 ? WW - 1 : ix);
                iy = iy < 0 ? 0 : (iy > HH - 1 ? HH - 1 : iy);
                vB[k] = map_b[iy * WW + ix];
            }
        }
    }

    // ---- phase 2: masks + per-row nearest-free-column min ----
    float acc = 0.0f;
    #pragma unroll
    for (int k = 0; k < 2; ++k) {
        if (k >= kn) continue;                     // wave-uniform
        const int clA = (vA[k] == 0.0f) ? 1 : 0;   // offroad==1 <=> drv==0 ({0,1} map)
        const int clB = (vB[k] == 0.0f) ? 1 : 0;
        const unsigned long long cmA = __ballot(clA);
        const unsigned long long cmB = __ballot(clB);
        const int ncoll = __popcll(cmA) + __popcll(cmB);
        if (ncoll == 0 || ncoll == PP) continue;   // overlap false -> contributes 0

        // 10-bit FREE-column mask per grid row (wave-uniform -> SALU)
        const unsigned long long fA = ~cmA;                           // points 0..63
        const unsigned long long fB = (~cmB) & ((1ull << 36) - 1ull); // points 64..99
        unsigned rows[10], revs[10];
        #pragma unroll
        for (int r = 0; r < 6; ++r) rows[r] = (unsigned)((fA >> (10 * r)) & 0x3FFull);
        rows[6] = (unsigned)(((fA >> 60) | (fB << 4)) & 0x3FFull);
        #pragma unroll
        for (int r = 7; r < 10; ++r) rows[r] = (unsigned)((fB >> (10 * r - 64)) & 0x3FFull);
        #pragma unroll
        for (int r = 0; r < 10; ++r) revs[r] = __brev(rows[r]) >> 22;   // 10-bit reverse

        // Merged A/B per-row nearest-free-column min.
        // Empty row -> marker bit 25 -> d=25 -> 625*sy2 >= 30.9 > max real d2 (~26.9)
        float mA = 1e30f, mB = 1e30f;
        float diA = (float)iA * sx;
        float diB = (float)iB * sx;
        #pragma unroll
        for (int r = 0; r < 10; ++r) {
            const unsigned tA = (rows[r] >> jA) | (revs[r] >> invjA) | (1u << 25);
            const unsigned tB = (rows[r] >> jB) | (revs[r] >> invjB) | (1u << 25);
            const unsigned dA = __builtin_ctz(tA);
            const unsigned dB = __builtin_ctz(tB);
            mA = fminf(mA, fmaf(diA, diA, (float)(dA * dA) * sy2));
            mB = fminf(mB, fmaf(diB, diB, (float)(dB * dB) * sy2));
            diA -= sx;
            diB -= sx;
        }
        acc += clA ? (1.0f - sqrtf(mA) * inv_diag) : 0.0f;
        acc += clB ? (1.0f - sqrtf(mB) * inv_diag) : 0.0f;
    }

    // ---- wave reduce -> LDS -> block reduce ----
    #pragma unroll
    for (int off = 32; off > 0; off >>= 1) acc += __shfl_down(acc, off);
    if (lane == 0) s_part[wvu] = acc;
    __syncthreads();
    if (threadIdx.x < 64) {
        float v = (lane < NWAVE) ? s_part[lane] : 0.0f;
        v += __shfl_down(v, 8);
        v += __shfl_down(v, 4);
        v += __shfl_down(v, 2);
        v += __shfl_down(v, 1);
        if (lane == 0) {
            // RELAXED tagged-exchange rendezvous: payload rides in the atomic
            // itself (exchange returns prior value from the coherent point), so
            // no acquire/release fences -> no L2 writeback/invalidate (R11 bug).
            // No spin, no memset, self-cleaning (restores poison pattern).
            const unsigned long long tagged =
                (MAGICHI << 32) | (unsigned long long)__float_as_uint(v);
            const unsigned long long old = __hip_atomic_exchange(
                &ws[bn], tagged, __ATOMIC_RELAXED, __HIP_MEMORY_SCOPE_AGENT);
            if ((old >> 32) == MAGICHI) {
                const float other = __uint_as_float((unsigned)(old & 0xFFFFFFFFull));
                out[bn] = v + other;   // commutative -> bit-deterministic
                __hip_atomic_store(&ws[bn], CLEAN,
                                   __ATOMIC_RELAXED, __HIP_MEMORY_SCOPE_AGENT);
            }
        }
    }
}

extern "C" void kernel_launch(void* const* d_in, const int* in_sizes, int n_in,
                              void* d_out, int out_size, void* d_ws, size_t ws_size,
                              hipStream_t stream) {
    const float* x      = (const float*)d_in[0];
    const float* dmap   = (const float*)d_in[1];
    const float* extent = (const float*)d_in[2];
    const float* rfa    = (const float*)d_in[3];
    float* out = (float*)d_out;
    unsigned long long* ws = (unsigned long long*)d_ws;   // 256 x u64 = 2 KB

    mapcoll_fused<<<BB * NN * 2, NWAVE * 64, 0, stream>>>(x, dmap, extent, rfa, ws, out);
}

// Round 13
// 11.073 us; speedup vs baseline: 2.0149x; 1.3250x over previous
//
#include <hip/hip_runtime.h>
#include <math.h>

// Problem constants from the reference
#define BB 32
#define NN 8
#define TT 52
#define HH 224
#define WW 224
#define PP 100    // 10x10 local grid; point p: slot A = lane p (p<64), slot B = lane p-64
#define NWAVE 16  // waves per block (1024 threads); block = one (b,n) output

__device__ __forceinline__ float rlane_f(float v, int l) {
    return __int_as_float(__builtin_amdgcn_readlane(__float_as_int(v), l));
}

__global__ __launch_bounds__(NWAVE * 64) void mapcoll_fused(
    const float* __restrict__ x,        // (B,N,T,6)
    const float* __restrict__ dmap,     // (B,H,W)
    const float* __restrict__ extent,   // (B,3)
    const float* __restrict__ rfa,      // (B,3,3)
    float* __restrict__ out)            // (B*N)
{
    const int bn   = blockIdx.x;        // 0..255
    const int b    = bn >> 3;           // NN == 8
    const int lane = threadIdx.x & 63;
    const int wvu  = __builtin_amdgcn_readfirstlane((int)(threadIdx.x >> 6));

    __shared__ float s_w[NWAVE][128];   // per-wave dj^2*sy^2 table, idx = r*10+j
    __shared__ float s_part[NWAVE];

    // ---- per-b uniforms (scalar loads) ----
    const float lwx = extent[b * 3 + 0];
    const float lwy = extent[b * 3 + 1];
    const float inv_diag = 1.0f / sqrtf(lwx * lwx + lwy * lwy);
    const float r00 = rfa[b*9+0], r01 = rfa[b*9+1], r02 = rfa[b*9+2];
    const float r10 = rfa[b*9+3], r11 = rfa[b*9+4], r12 = rfa[b*9+5];
    const float* __restrict__ map_b = dmap + (size_t)b * (HH * WW);
    // Rigid-motion invariance: |a_p - a_q|^2 = ((i_p-i_q)*sx)^2 + ((j_p-j_q)*sy)^2
    const float sx  = lwx * (1.0f / 9.0f);
    const float sy  = lwy * (1.0f / 9.0f);
    const float sy2 = sy * sy;

    // ---- lane-parallel prologue: lane t<52 builds fused transform uniforms ----
    // pix = agt @ rfa[:2,:2]^T + rfa[:2,2] with agt = pts@rot + pos folds to
    // fx = p0*u00 + p1*u01 + u0c ; fy = p0*u10 + p1*u11 + u1c   (per-t uniforms)
    float u00 = 0.f, u01 = 0.f, u0c = 0.f, u10 = 0.f, u11 = 0.f, u1c = 0.f;
    if (lane < TT) {
        const int base = (bn * TT + lane) * 6;
        const float2 p2 = *reinterpret_cast<const float2*>(x + base);
        const float yw = x[base + 3];
        const float sn = __sinf(yw), cs = __cosf(yw);
        u00 = cs * r00 + sn * r01;
        u01 = cs * r01 - sn * r00;
        u0c = p2.x * r00 + p2.y * r01 + r02;
        u10 = cs * r10 + sn * r11;
        u11 = cs * r11 - sn * r10;
        u1c = p2.x * r10 + p2.y * r11 + r12;
    }

    // ---- per-lane geometry (t-invariant) ----
    const int iA = lane / 10, jA = lane - iA * 10;
    const int pB = lane + 64;
    const int iB = pB / 10,   jB = pB - iB * 10;
    const bool hasB = (lane < PP - 64);   // 36 lanes own a B point
    const float p0A = (-0.5f + (float)iA * (1.0f/9.0f)) * lwx;
    const float p1A = (-0.5f + (float)jA * (1.0f/9.0f)) * lwy;
    const float p0B = (-0.5f + (float)iB * (1.0f/9.0f)) * lwx;
    const float p1B = (-0.5f + (float)jB * (1.0f/9.0f)) * lwy;

    // scan shift constants (per-lane, t-invariant); &63 / max0 keep shifts defined
    const int shA  = (10 * iA) & 63;                       // into fA (valid iA<6)
    const int sGA  = (10 * iA - 60) < 0 ? 0 : (10 * iA - 60);  // into G (iA>=6)
    const int sGB  = ((10 * iB - 60) & 63);                // B always uses G (iB>=6)
    const int rshA = 31 - jA;                              // brev fold shift
    const int rshB = 31 - jB;

    // di^2 tables (hoisted out of the t loop)
    float di2A[10], di2B[10];
    #pragma unroll
    for (int r = 0; r < 10; ++r) {
        const float dA = (float)(iA - r) * sx; di2A[r] = dA * dA;
        const float dB = (float)(iB - r) * sx; di2B[r] = dB * dB;
    }

    float* wtab = &s_w[wvu][0];
    const unsigned MARK = 1u << 25;   // empty-row sentinel: d=25 -> 625*sy2 > 26.9 max

    // t distribution: waves 0..3 -> 4 t's, waves 4..15 -> 3 t's (52 total)
    const int kn = (wvu < 4) ? 4 : 3;
    const int t0 = (wvu < 4) ? (wvu * 4) : (16 + (wvu - 4) * 3);

    float acc = 0.0f;
    #pragma unroll
    for (int k = 0; k < 4; ++k) {
        if (k < kn) {                          // wave-uniform guard
            const int t = t0 + k;
            const float a00 = rlane_f(u00, t), a01 = rlane_f(u01, t), a0c = rlane_f(u0c, t);
            const float a10 = rlane_f(u10, t), a11 = rlane_f(u11, t), a1c = rlane_f(u1c, t);

            // rasterize + gather both slots (trunc cast then clip, ref semantics)
            float vAv, vBv = 1.0f;
            {
                const float fx = fmaf(p0A, a00, fmaf(p1A, a01, a0c));
                const float fy = fmaf(p0A, a10, fmaf(p1A, a11, a1c));
                int ix = (int)fx, iy = (int)fy;
                ix = ix < 0 ? 0 : (ix > WW - 1 ? WW - 1 : ix);
                iy = iy < 0 ? 0 : (iy > HH - 1 ? HH - 1 : iy);
                vAv = map_b[iy * WW + ix];
            }
            if (hasB) {
                const float fx = fmaf(p0B, a00, fmaf(p1B, a01, a0c));
                const float fy = fmaf(p0B, a10, fmaf(p1B, a11, a1c));
                int ix = (int)fx, iy = (int)fy;
                ix = ix < 0 ? 0 : (ix > WW - 1 ? WW - 1 : ix);
                iy = iy < 0 ? 0 : (iy > HH - 1 ? HH - 1 : iy);
                vBv = map_b[iy * WW + ix];
            }

            const int clA = (vAv == 0.0f) ? 1 : 0;  // offroad==1 <=> drv==0 ({0,1} map)
            const int clB = (vBv == 0.0f) ? 1 : 0;
            const unsigned long long cmA = __ballot(clA);
            const unsigned long long cmB = __ballot(clB);
            const int ncoll = __popcll(cmA) + __popcll(cmB);
            if (ncoll != 0 && ncoll != PP) {       // overlap true (wave-uniform)
                // 100-bit FREE mask F = fA | fB<<64 ; G = F>>60 (covers rows 6..9)
                const unsigned long long fA = ~cmA;
                const unsigned long long fB = (~cmB) & ((1ull << 36) - 1ull);
                const unsigned long long G  = (fA >> 60) | (fB << 4);

                // per-lane scan: nearest free column in OWN row, both slots
                // slot A (row iA): mask = bits [10iA,10iA+10) of F
                {
                    const unsigned loA = (unsigned)(fA >> shA);
                    const unsigned gA  = (unsigned)(G  >> sGA);
                    const unsigned m10 = ((iA < 6) ? loA : gA) & 0x3FFu;
                    const unsigned tt  = (m10 >> jA) | (__brev(m10) >> rshA) | MARK;
                    const float d  = (float)__builtin_ctz(tt);
                    const float ds = d * sy;
                    wtab[lane] = ds * ds;          // w[p=lane]
                }
                // slot B (row iB>=6): always G path
                if (hasB) {
                    const unsigned m10 = ((unsigned)(G >> sGB)) & 0x3FFu;
                    const unsigned tt  = (m10 >> jB) | (__brev(m10) >> rshB) | MARK;
                    const float d  = (float)__builtin_ctz(tt);
                    const float ds = d * sy;
                    wtab[lane + 64] = ds * ds;     // w[p=lane+64]
                }
                // same-wave LDS write -> read ordering
                asm volatile("s_waitcnt lgkmcnt(0)" ::: "memory");
                __builtin_amdgcn_wave_barrier();

                // mind2 = min_r( di2[r] + w[r*10+j] )  (LDS reads on LDS pipe)
                float mA = 1e30f, mB = 1e30f;
                #pragma unroll
                for (int r = 0; r < 10; r += 2) {
                    const float wA0 = wtab[r * 10 + jA];
                    const float wA1 = wtab[r * 10 + 10 + jA];
                    mA = fminf(mA, fminf(di2A[r] + wA0, di2A[r + 1] + wA1));
                    const float wB0 = wtab[r * 10 + jB];
                    const float wB1 = wtab[r * 10 + 10 + jB];
                    mB = fminf(mB, fminf(di2B[r] + wB0, di2B[r + 1] + wB1));
                }
                acc += clA ? (1.0f - sqrtf(mA) * inv_diag) : 0.0f;
                acc += clB ? (1.0f - sqrtf(mB) * inv_diag) : 0.0f;
            }
        }
    }

    // ---- wave reduce -> LDS -> block reduce -> single store ----
    #pragma unroll
    for (int off = 32; off > 0; off >>= 1) acc += __shfl_down(acc, off);
    if (lane == 0) s_part[wvu] = acc;
    __syncthreads();
    if (threadIdx.x < 64) {
        float v = (lane < NWAVE) ? s_part[lane] : 0.0f;
        v += __shfl_down(v, 8);
        v += __shfl_down(v, 4);
        v += __shfl_down(v, 2);
        v += __shfl_down(v, 1);
        if (lane == 0) out[bn] = v;   // every output written -> no memset needed
    }
}

extern "C" void kernel_launch(void* const* d_in, const int* in_sizes, int n_in,
                              void* d_out, int out_size, void* d_ws, size_t ws_size,
                              hipStream_t stream) {
    const float* x      = (const float*)d_in[0];
    const float* dmap   = (const float*)d_in[1];
    const float* extent = (const float*)d_in[2];
    const float* rfa    = (const float*)d_in[3];
    float* out = (float*)d_out;

    mapcoll_fused<<<BB * NN, NWAVE * 64, 0, stream>>>(x, dmap, extent, rfa, out);
}